// Round 14
// baseline (106.583 us; speedup 1.0000x reference)
//
#include <hip/hip_runtime.h>
#include <math.h>

#define BB 4
#define NN 512
#define FIN 256
#define NH 8
#define FD 32
#define HF 256               // NH * FD
// leaky(x) = max(x, 0.21x) = CA*x + CB*|x|
#define CA 0.605f
#define CB 0.395f
#define IT 32                // i-tile rows; grid 512 = 2 blocks/CU
#define ESTR 268             // uints/e_s row: 1072B, 16B-aligned
#define GTS 260              // grT row stride in uints (16B-aligned)
#define GLX(j) ((j) ^ (((j) >> 5) & 7))
#define ALX(j) ((j) + ((j) >> 5))

typedef _Float16 h2_t __attribute__((ext_vector_type(2)));
union H2U { unsigned u; h2_t h; };
typedef __fp16 v8h __attribute__((ext_vector_type(8)));  // MFMA a/b frag
typedef float v4f __attribute__((ext_vector_type(4)));   // MFMA acc
union U8 { uint4 u4; v8h h; };

__device__ __forceinline__ h2_t pkrtz(float a, float b) {
  auto r = __builtin_amdgcn_cvt_pkrtz(a, b);
  union { decltype(r) f; h2_t h; } u;
  u.f = r;
  return u.h;
}
__device__ __forceinline__ unsigned pkrtz_u(float a, float b) {
  H2U u; u.h = pkrtz(a, b);
  return u.u;
}

// x = g2 + q2 (v_pk_add_f16); |x| (v_and 0x7fff7fff); acc += u2.|x| (v_dot2)
__device__ __forceinline__ float acc2(unsigned g, h2_t q, h2_t u, float acc) {
  H2U v; v.u = g;
  h2_t s = v.h + q;
  H2U a; a.h = s; a.u &= 0x7fff7fffu;
  return __builtin_amdgcn_fdot2(a.h, u, acc, false);
}

// 32-feature score for one j from 4 uint4 (8 fp16 each)
__device__ __forceinline__ float score16(uint4 g0, uint4 g1, uint4 g2, uint4 g3,
                                         const h2_t* qh, const h2_t* uh,
                                         float init) {
  float e0 = init, e1 = 0.f;
  e0 = acc2(g0.x, qh[0], uh[0], e0);
  e1 = acc2(g0.y, qh[1], uh[1], e1);
  e0 = acc2(g0.z, qh[2], uh[2], e0);
  e1 = acc2(g0.w, qh[3], uh[3], e1);
  e0 = acc2(g1.x, qh[4], uh[4], e0);
  e1 = acc2(g1.y, qh[5], uh[5], e1);
  e0 = acc2(g1.z, qh[6], uh[6], e0);
  e1 = acc2(g1.w, qh[7], uh[7], e1);
  e0 = acc2(g2.x, qh[8], uh[8], e0);
  e1 = acc2(g2.y, qh[9], uh[9], e1);
  e0 = acc2(g2.z, qh[10], uh[10], e0);
  e1 = acc2(g2.w, qh[11], uh[11], e1);
  e0 = acc2(g3.x, qh[12], uh[12], e0);
  e1 = acc2(g3.y, qh[13], uh[13], e1);
  e0 = acc2(g3.z, qh[14], uh[14], e0);
  e1 = acc2(g3.w, qh[15], uh[15], e1);
  return e0 + e1;
}

// ---------------------------------------------------------------------------
// Kernel 1: dual GEMM g = h @ W, both outputs fp16. (unchanged)
// ---------------------------------------------------------------------------
__global__ __launch_bounds__(256) void gemm_dual(
    const float* __restrict__ h, const float* __restrict__ Wl,
    const float* __restrict__ Wr, _Float16* __restrict__ glh,
    _Float16* __restrict__ grh) {
  const int t = threadIdx.x;
  const int row0 = blockIdx.x * 8;
  const float* __restrict__ W = blockIdx.y ? Wr : Wl;

  float acc[8] = {0.f, 0.f, 0.f, 0.f, 0.f, 0.f, 0.f, 0.f};
  const float* Wp = W + t;
  const float* hp = h + (size_t)row0 * FIN;

#pragma unroll 2
  for (int k4 = 0; k4 < FIN / 4; ++k4) {
    float4 hv[8];
#pragma unroll
    for (int r = 0; r < 8; ++r)
      hv[r] = *(const float4*)(hp + r * FIN + 4 * k4);
#pragma unroll
    for (int kk = 0; kk < 4; ++kk) {
      const float w = Wp[(size_t)(4 * k4 + kk) * HF];
#pragma unroll
      for (int r = 0; r < 8; ++r) {
        const float hval = (kk == 0) ? hv[r].x
                         : (kk == 1) ? hv[r].y
                         : (kk == 2) ? hv[r].z : hv[r].w;
        acc[r] = fmaf(hval, w, acc[r]);
      }
    }
  }

  _Float16* gp = (blockIdx.y ? grh : glh) + (size_t)row0 * HF + t;
#pragma unroll
  for (int r = 0; r < 8; ++r) gp[(size_t)r * HF] = (_Float16)acc[r];
}

// ---------------------------------------------------------------------------
// Kernel 2: fused GATv2 attention. Block = (head hh, 32-row i-tile, batch b).
// R14 = R12 base, but phase 1 computes 4 rows/thread x 16 j: one gl read
// feeds 4 score16 -> phase-1 LDS traffic 512 -> 256 KB/block (R13 analysis:
// phase 1 was LDS-BW-bound at ~10 us/CU with 1 row/thread). VALU unchanged.
// Exp-at-write softmax (no max pass), MFMA phase 3, fp16 everywhere.
// ---------------------------------------------------------------------------
__global__ __launch_bounds__(256, 2) void gat_attn(
    const _Float16* __restrict__ glh, const _Float16* __restrict__ grh,
    const int* __restrict__ adj, const float* __restrict__ aw,
    float* __restrict__ out) {
  __shared__ __align__(16) unsigned ubuf[32 * GTS];  // 33.3 KB gl4/grT union
  __shared__ __align__(16) unsigned e_s[IT][ESTR];   // 34.3 KB fp16 p
  __shared__ float Al_s[544];                        // 2.1 KB, ALX-skewed
  __shared__ float s_part[32][33];                   // 4.2 KB row-sum parts
  __shared__ float inv_l[IT];

  const int t = threadIdx.x;
  const int hh = blockIdx.x;
  const int i0 = blockIdx.y * IT;
  const int b = blockIdx.z;
  const int r0 = t & 7;    // phase-1 rows {r0, r0+8, r0+16, r0+24}
  const int jg = t >> 3;   // 0..31, 16 j each

  uint4* gl4 = (uint4*)ubuf;  // [k4*512 + GLX(j)], k-major

  const _Float16* glp = glh + (size_t)b * NN * HF + hh * FD;

  // ---- per-thread prep: aw -> wv/uh; 4 q rows -> qhA..qhD + a_rA..D ----
  h2_t wv[16], uh[16], qhA[16], qhB[16], qhC[16], qhD[16];
  float a_rA = 0.f, a_rB = 0.f, a_rC = 0.f, a_rD = 0.f;
  {
#pragma unroll
    for (int f4 = 0; f4 < 8; ++f4) {
      const float4 w4 = *(const float4*)(aw + 4 * f4);
      wv[2 * f4] = pkrtz(CA * w4.x, CA * w4.y);
      wv[2 * f4 + 1] = pkrtz(CA * w4.z, CA * w4.w);
      uh[2 * f4] = pkrtz(CB * w4.x, CB * w4.y);
      uh[2 * f4 + 1] = pkrtz(CB * w4.z, CB * w4.w);
    }
#define LDQ(QH, AR, ROW)                                                    \
  {                                                                         \
    const uint4* qa =                                                       \
        (const uint4*)(grh + (size_t)(b * NN + i0 + (ROW)) * HF + hh * FD); \
    const uint4 q0 = qa[0], q1 = qa[1], q2 = qa[2], q3 = qa[3];             \
    H2U z;                                                                  \
    z.u = q0.x; QH[0] = z.h;  z.u = q0.y; QH[1] = z.h;                      \
    z.u = q0.z; QH[2] = z.h;  z.u = q0.w; QH[3] = z.h;                      \
    z.u = q1.x; QH[4] = z.h;  z.u = q1.y; QH[5] = z.h;                      \
    z.u = q1.z; QH[6] = z.h;  z.u = q1.w; QH[7] = z.h;                      \
    z.u = q2.x; QH[8] = z.h;  z.u = q2.y; QH[9] = z.h;                      \
    z.u = q2.z; QH[10] = z.h; z.u = q2.w; QH[11] = z.h;                     \
    z.u = q3.x; QH[12] = z.h; z.u = q3.y; QH[13] = z.h;                     \
    z.u = q3.z; QH[14] = z.h; z.u = q3.w; QH[15] = z.h;                     \
    _Pragma("unroll") for (int f2 = 0; f2 < 16; ++f2)                       \
        AR = __builtin_amdgcn_fdot2(QH[f2], wv[f2], AR, false);             \
  }
    LDQ(qhA, a_rA, r0)
    LDQ(qhB, a_rB, r0 + 8)
    LDQ(qhC, a_rC, r0 + 16)
    LDQ(qhD, a_rD, r0 + 24)
#undef LDQ
  }

  // ---- pre-pass: stage gl slice -> LDS (GLX) + Al (ALX) ----
#pragma unroll
  for (int c = 0; c < 2; ++c) {
    const int j = t + 256 * c;
    const uint4* gp = (const uint4*)(glp + (size_t)j * HF);
    const uint4 g0 = gp[0], g1 = gp[1], g2 = gp[2], g3 = gp[3];
    const int jx = GLX(j);
    gl4[0 * NN + jx] = g0;
    gl4[1 * NN + jx] = g1;
    gl4[2 * NN + jx] = g2;
    gl4[3 * NN + jx] = g3;
    float s0 = 0.f, s1 = 0.f;
    H2U v;
#define ALD(gu, i)                                                  \
  v.u = gu.x; s0 = __builtin_amdgcn_fdot2(v.h, wv[i+0], s0, false); \
  v.u = gu.y; s1 = __builtin_amdgcn_fdot2(v.h, wv[i+1], s1, false); \
  v.u = gu.z; s0 = __builtin_amdgcn_fdot2(v.h, wv[i+2], s0, false); \
  v.u = gu.w; s1 = __builtin_amdgcn_fdot2(v.h, wv[i+3], s1, false);
    ALD(g0, 0) ALD(g1, 4) ALD(g2, 8) ALD(g3, 12)
#undef ALD
    Al_s[ALX(j)] = s0 + s1;
  }
  __syncthreads();

  // ---- phase 1: p = exp(e) for 4 rows x 16 j; one gl read / 4 rows ----
  {
    unsigned* erow0 = &e_s[r0][jg * 8];
    unsigned* erow1 = &e_s[r0 + 8][jg * 8];
    unsigned* erow2 = &e_s[r0 + 16][jg * 8];
    unsigned* erow3 = &e_s[r0 + 24][jg * 8];
    const int* adjp0 = adj + (size_t)(i0 + r0) * NN + jg * 16;
    const int* adjp1 = adjp0 + 8 * NN;
    const int* adjp2 = adjp0 + 16 * NN;
    const int* adjp3 = adjp0 + 24 * NN;
    float sA = 0.f, sB = 0.f, sC = 0.f, sD = 0.f;
#pragma unroll
    for (int g4 = 0; g4 < 4; ++g4) {
      const int4 m0 = ((const int4*)adjp0)[g4];
      const int4 m1 = ((const int4*)adjp1)[g4];
      const int4 m2 = ((const int4*)adjp2)[g4];
      const int4 m3 = ((const int4*)adjp3)[g4];
      float pA[4], pB[4], pC[4], pD[4];
#pragma unroll
      for (int k = 0; k < 4; ++k) {
        const int j = jg * 16 + 4 * g4 + k;
        const int jx = GLX(j);
        const uint4 g0 = gl4[0 * NN + jx], g1 = gl4[1 * NN + jx];
        const uint4 g2 = gl4[2 * NN + jx], g3 = gl4[3 * NN + jx];
        const float al = Al_s[ALX(j)];
        const float eA = score16(g0, g1, g2, g3, qhA, uh, al + a_rA);
        const float eB = score16(g0, g1, g2, g3, qhB, uh, al + a_rB);
        const float eC = score16(g0, g1, g2, g3, qhC, uh, al + a_rC);
        const float eD = score16(g0, g1, g2, g3, qhD, uh, al + a_rD);
        const int k0 = (k == 0) ? m0.x : (k == 1) ? m0.y : (k == 2) ? m0.z : m0.w;
        const int k1 = (k == 0) ? m1.x : (k == 1) ? m1.y : (k == 2) ? m1.z : m1.w;
        const int k2 = (k == 0) ? m2.x : (k == 1) ? m2.y : (k == 2) ? m2.z : m2.w;
        const int k3 = (k == 0) ? m3.x : (k == 1) ? m3.y : (k == 2) ? m3.z : m3.w;
        pA[k] = k0 ? __expf(eA) : 0.f;
        pB[k] = k1 ? __expf(eB) : 0.f;
        pC[k] = k2 ? __expf(eC) : 0.f;
        pD[k] = k3 ? __expf(eD) : 0.f;
      }
      sA += (pA[0] + pA[1]) + (pA[2] + pA[3]);
      sB += (pB[0] + pB[1]) + (pB[2] + pB[3]);
      sC += (pC[0] + pC[1]) + (pC[2] + pC[3]);
      sD += (pD[0] + pD[1]) + (pD[2] + pD[3]);
      uint2 w0;
      w0.x = pkrtz_u(pA[0], pA[1]); w0.y = pkrtz_u(pA[2], pA[3]);
      *(uint2*)&erow0[2 * g4] = w0;
      w0.x = pkrtz_u(pB[0], pB[1]); w0.y = pkrtz_u(pB[2], pB[3]);
      *(uint2*)&erow1[2 * g4] = w0;
      w0.x = pkrtz_u(pC[0], pC[1]); w0.y = pkrtz_u(pC[2], pC[3]);
      *(uint2*)&erow2[2 * g4] = w0;
      w0.x = pkrtz_u(pD[0], pD[1]); w0.y = pkrtz_u(pD[2], pD[3]);
      *(uint2*)&erow3[2 * g4] = w0;
    }
    s_part[jg][r0] = sA;
    s_part[jg][r0 + 8] = sB;
    s_part[jg][r0 + 16] = sC;
    s_part[jg][r0 + 24] = sD;
  }
  __syncthreads();

  // ---- phase 2': stage grT (fp16 v_perm) + row-sum reduce ----
  {
    const int fq = t & 7;    // f-quad
    const int jp0 = t >> 3;  // 0..31 (j-pair)
    const unsigned* gbase =
        (const unsigned*)(grh + (size_t)b * NN * HF + hh * FD) + 2 * fq;
#pragma unroll
    for (int s2 = 0; s2 < 8; ++s2) {
      const int jp = jp0 + 32 * s2;
      const uint2 A = *(const uint2*)(gbase + (size_t)(2 * jp) * 128);
      const uint2 Bv = *(const uint2*)(gbase + (size_t)(2 * jp + 1) * 128);
      // low16 = even j (matches pkrtz packing of p in e_s)
      ubuf[(4 * fq + 0) * GTS + jp] = __builtin_amdgcn_perm(Bv.x, A.x, 0x05040100u);
      ubuf[(4 * fq + 1) * GTS + jp] = __builtin_amdgcn_perm(Bv.x, A.x, 0x07060302u);
      ubuf[(4 * fq + 2) * GTS + jp] = __builtin_amdgcn_perm(Bv.y, A.y, 0x05040100u);
      ubuf[(4 * fq + 3) * GTS + jp] = __builtin_amdgcn_perm(Bv.y, A.y, 0x07060302u);
    }
    if (t < IT) {
      float s = 0.f;
#pragma unroll
      for (int c = 0; c < 32; ++c) s += s_part[c][t];
      inv_l[t] = 1.f / s;
    }
  }
  __syncthreads();

  // ---- phase 3: MFMA GEMM  C[32x32] = P . grT^T, one 16x16 tile/wave ----
  {
    const int lane = t & 63;
    const int wv3 = t >> 6;          // 0..3
    const int Mt = wv3 & 1, Nt = wv3 >> 1;
    const int l16 = lane & 15, q = lane >> 4;
    const unsigned* arow = &e_s[Mt * 16 + l16][0];       // A[m][k] packed p
    const unsigned* brow = &ubuf[(Nt * 16 + l16) * GTS]; // B[k][n]=grT[n][k]
    v4f acc = {0.f, 0.f, 0.f, 0.f};
#pragma unroll
    for (int s = 0; s < 16; ++s) {
      U8 a; a.u4 = *(const uint4*)(arow + 16 * s + 4 * q);
      U8 bf; bf.u4 = *(const uint4*)(brow + 16 * s + 4 * q);
      acc = __builtin_amdgcn_mfma_f32_16x16x32_f16(a.h, bf.h, acc, 0, 0, 0);
    }
    // epilogue: D[row=q*4+r][col=l16], scale by inv_l, store
    float* op = out + (size_t)(b * NN + i0 + Mt * 16 + q * 4) * HF + hh * FD +
                Nt * 16 + l16;
#pragma unroll
    for (int r = 0; r < 4; ++r) {
      op[(size_t)r * HF] = acc[r] * inv_l[Mt * 16 + q * 4 + r];
    }
  }
}

// ---------------------------------------------------------------------------
extern "C" void kernel_launch(void* const* d_in, const int* in_sizes, int n_in,
                              void* d_out, int out_size, void* d_ws,
                              size_t ws_size, hipStream_t stream) {
  const float* h = (const float*)d_in[0];
  const int* adj = (const int*)d_in[1];
  const float* Wl = (const float*)d_in[2];
  const float* Wr = (const float*)d_in[3];
  const float* aw = (const float*)d_in[4];
  float* out = (float*)d_out;

  _Float16* glh = (_Float16*)d_ws;                                // 1 MB fp16
  _Float16* grh = (_Float16*)((char*)d_ws + (size_t)BB * NN * HF * 2);  // 1 MB

  dim3 gg(BB * NN / 8, 2, 1);
  gemm_dual<<<gg, 256, 0, stream>>>(h, Wl, Wr, glh, grh);

  dim3 ga(NH, NN / IT, BB);
  gat_attn<<<ga, 256, 0, stream>>>(glh, grh, adj, aw, out);
}

// Round 15
// 104.240 us; speedup vs baseline: 1.0225x; 1.0225x over previous
//
#include <hip/hip_runtime.h>
#include <math.h>

#define BB 4
#define NN 512
#define FIN 256
#define NH 8
#define FD 32
#define HF 256               // NH * FD
// leaky(x) = max(x, 0.21x) = CA*x + CB*|x|
#define CA 0.605f
#define CB 0.395f
#define IT 32                // i-tile rows; grid 512 = 2 blocks/CU
#define ESTR 268             // uints/e_s row: 1072B, 16B-aligned
#define GTS 260              // grT row stride in uints (16B-aligned)
#define GLX(j) ((j) ^ (((j) >> 5) & 7))
#define ALX(j) ((j) + ((j) >> 5))

typedef _Float16 h2_t __attribute__((ext_vector_type(2)));
union H2U { unsigned u; h2_t h; };
typedef __fp16 v8h __attribute__((ext_vector_type(8)));  // MFMA a/b frag
typedef float v4f __attribute__((ext_vector_type(4)));   // MFMA acc
union U8 { uint4 u4; v8h h; };

__device__ __forceinline__ h2_t pkrtz(float a, float b) {
  auto r = __builtin_amdgcn_cvt_pkrtz(a, b);
  union { decltype(r) f; h2_t h; } u;
  u.f = r;
  return u.h;
}
__device__ __forceinline__ unsigned pkrtz_u(float a, float b) {
  H2U u; u.h = pkrtz(a, b);
  return u.u;
}

// x = g2 + q2 (v_pk_add_f16); |x| (v_and 0x7fff7fff); acc += u2.|x| (v_dot2)
__device__ __forceinline__ float acc2(unsigned g, h2_t q, h2_t u, float acc) {
  H2U v; v.u = g;
  h2_t s = v.h + q;
  H2U a; a.h = s; a.u &= 0x7fff7fffu;
  return __builtin_amdgcn_fdot2(a.h, u, acc, false);
}

// 32-feature score for one j from 4 uint4 (8 fp16 each)
__device__ __forceinline__ float score16(uint4 g0, uint4 g1, uint4 g2, uint4 g3,
                                         const h2_t* qh, const h2_t* uh,
                                         float init) {
  float e0 = init, e1 = 0.f;
  e0 = acc2(g0.x, qh[0], uh[0], e0);
  e1 = acc2(g0.y, qh[1], uh[1], e1);
  e0 = acc2(g0.z, qh[2], uh[2], e0);
  e1 = acc2(g0.w, qh[3], uh[3], e1);
  e0 = acc2(g1.x, qh[4], uh[4], e0);
  e1 = acc2(g1.y, qh[5], uh[5], e1);
  e0 = acc2(g1.z, qh[6], uh[6], e0);
  e1 = acc2(g1.w, qh[7], uh[7], e1);
  e0 = acc2(g2.x, qh[8], uh[8], e0);
  e1 = acc2(g2.y, qh[9], uh[9], e1);
  e0 = acc2(g2.z, qh[10], uh[10], e0);
  e1 = acc2(g2.w, qh[11], uh[11], e1);
  e0 = acc2(g3.x, qh[12], uh[12], e0);
  e1 = acc2(g3.y, qh[13], uh[13], e1);
  e0 = acc2(g3.z, qh[14], uh[14], e0);
  e1 = acc2(g3.w, qh[15], uh[15], e1);
  return e0 + e1;
}

// ---------------------------------------------------------------------------
// Kernel 1: dual GEMM g = h @ W, both outputs fp16.
// ---------------------------------------------------------------------------
__global__ __launch_bounds__(256) void gemm_dual(
    const float* __restrict__ h, const float* __restrict__ Wl,
    const float* __restrict__ Wr, _Float16* __restrict__ glh,
    _Float16* __restrict__ grh) {
  const int t = threadIdx.x;
  const int row0 = blockIdx.x * 8;
  const float* __restrict__ W = blockIdx.y ? Wr : Wl;

  float acc[8] = {0.f, 0.f, 0.f, 0.f, 0.f, 0.f, 0.f, 0.f};
  const float* Wp = W + t;
  const float* hp = h + (size_t)row0 * FIN;

#pragma unroll 2
  for (int k4 = 0; k4 < FIN / 4; ++k4) {
    float4 hv[8];
#pragma unroll
    for (int r = 0; r < 8; ++r)
      hv[r] = *(const float4*)(hp + r * FIN + 4 * k4);
#pragma unroll
    for (int kk = 0; kk < 4; ++kk) {
      const float w = Wp[(size_t)(4 * k4 + kk) * HF];
#pragma unroll
      for (int r = 0; r < 8; ++r) {
        const float hval = (kk == 0) ? hv[r].x
                         : (kk == 1) ? hv[r].y
                         : (kk == 2) ? hv[r].z : hv[r].w;
        acc[r] = fmaf(hval, w, acc[r]);
      }
    }
  }

  _Float16* gp = (blockIdx.y ? grh : glh) + (size_t)row0 * HF + t;
#pragma unroll
  for (int r = 0; r < 8; ++r) gp[(size_t)r * HF] = (_Float16)acc[r];
}

// ---------------------------------------------------------------------------
// Kernel 2: fused GATv2 attention. Block = (head hh, 32-row i-tile, batch b).
// R12 configuration (session best, 103.7 us): exp-at-write softmax (no
// max-pass; shift-invariant, e bounded ~|2|, masked p = 0 exactly), phase 1
// computes 2 rows/thread sharing gl reads, gl staged in LDS (GLX swizzle),
// grT fp16 staging via v_perm, phase 3 = MFMA C[32x32] = P . grT.
// ---------------------------------------------------------------------------
__global__ __launch_bounds__(256, 2) void gat_attn(
    const _Float16* __restrict__ glh, const _Float16* __restrict__ grh,
    const int* __restrict__ adj, const float* __restrict__ aw,
    float* __restrict__ out) {
  __shared__ __align__(16) unsigned ubuf[32 * GTS];  // 33.3 KB gl4/grT union
  __shared__ __align__(16) unsigned e_s[IT][ESTR];   // 34.3 KB fp16 p
  __shared__ float Al_s[544];                        // 2.1 KB, ALX-skewed
  __shared__ float s_part[16][33];                   // 2.1 KB row-sum parts
  __shared__ float inv_l[IT];

  const int t = threadIdx.x;
  const int hh = blockIdx.x;
  const int i0 = blockIdx.y * IT;
  const int b = blockIdx.z;
  const int r0 = t & 15;   // phase-1 rows {r0, r0+16}
  const int jg = t >> 4;   // 0..15, 32 j each

  uint4* gl4 = (uint4*)ubuf;  // [k4*512 + GLX(j)], k-major

  const _Float16* glp = glh + (size_t)b * NN * HF + hh * FD;

  // ---- per-thread prep: aw -> wv/uh; q rows r0 & r0+16 -> qh/qh2 + a_r ----
  h2_t wv[16], uh[16], qh[16], qh2[16];
  float a_r0 = 0.f, a_r1 = 0.f;
  {
#pragma unroll
    for (int f4 = 0; f4 < 8; ++f4) {
      const float4 w4 = *(const float4*)(aw + 4 * f4);
      wv[2 * f4] = pkrtz(CA * w4.x, CA * w4.y);
      wv[2 * f4 + 1] = pkrtz(CA * w4.z, CA * w4.w);
      uh[2 * f4] = pkrtz(CB * w4.x, CB * w4.y);
      uh[2 * f4 + 1] = pkrtz(CB * w4.z, CB * w4.w);
    }
    const uint4* qa =
        (const uint4*)(grh + (size_t)(b * NN + i0 + r0) * HF + hh * FD);
    const uint4* qb =
        (const uint4*)(grh + (size_t)(b * NN + i0 + r0 + 16) * HF + hh * FD);
    const uint4 q0 = qa[0], q1 = qa[1], q2 = qa[2], q3 = qa[3];
    const uint4 p0 = qb[0], p1 = qb[1], p2 = qb[2], p3 = qb[3];
    H2U z;
    z.u = q0.x; qh[0] = z.h;  z.u = q0.y; qh[1] = z.h;
    z.u = q0.z; qh[2] = z.h;  z.u = q0.w; qh[3] = z.h;
    z.u = q1.x; qh[4] = z.h;  z.u = q1.y; qh[5] = z.h;
    z.u = q1.z; qh[6] = z.h;  z.u = q1.w; qh[7] = z.h;
    z.u = q2.x; qh[8] = z.h;  z.u = q2.y; qh[9] = z.h;
    z.u = q2.z; qh[10] = z.h; z.u = q2.w; qh[11] = z.h;
    z.u = q3.x; qh[12] = z.h; z.u = q3.y; qh[13] = z.h;
    z.u = q3.z; qh[14] = z.h; z.u = q3.w; qh[15] = z.h;
    z.u = p0.x; qh2[0] = z.h;  z.u = p0.y; qh2[1] = z.h;
    z.u = p0.z; qh2[2] = z.h;  z.u = p0.w; qh2[3] = z.h;
    z.u = p1.x; qh2[4] = z.h;  z.u = p1.y; qh2[5] = z.h;
    z.u = p1.z; qh2[6] = z.h;  z.u = p1.w; qh2[7] = z.h;
    z.u = p2.x; qh2[8] = z.h;  z.u = p2.y; qh2[9] = z.h;
    z.u = p2.z; qh2[10] = z.h; z.u = p2.w; qh2[11] = z.h;
    z.u = p3.x; qh2[12] = z.h; z.u = p3.y; qh2[13] = z.h;
    z.u = p3.z; qh2[14] = z.h; z.u = p3.w; qh2[15] = z.h;
#pragma unroll
    for (int f2 = 0; f2 < 16; ++f2) {
      a_r0 = __builtin_amdgcn_fdot2(qh[f2], wv[f2], a_r0, false);
      a_r1 = __builtin_amdgcn_fdot2(qh2[f2], wv[f2], a_r1, false);
    }
  }

  // ---- pre-pass: stage gl slice -> LDS (GLX-swizzled) + Al (ALX) ----
#pragma unroll
  for (int c = 0; c < 2; ++c) {
    const int j = t + 256 * c;
    const uint4* gp = (const uint4*)(glp + (size_t)j * HF);
    const uint4 g0 = gp[0], g1 = gp[1], g2 = gp[2], g3 = gp[3];
    const int jx = GLX(j);
    gl4[0 * NN + jx] = g0;
    gl4[1 * NN + jx] = g1;
    gl4[2 * NN + jx] = g2;
    gl4[3 * NN + jx] = g3;
    float s0 = 0.f, s1 = 0.f;
    H2U v;
#define ALD(gu, i)                                                  \
  v.u = gu.x; s0 = __builtin_amdgcn_fdot2(v.h, wv[i+0], s0, false); \
  v.u = gu.y; s1 = __builtin_amdgcn_fdot2(v.h, wv[i+1], s1, false); \
  v.u = gu.z; s0 = __builtin_amdgcn_fdot2(v.h, wv[i+2], s0, false); \
  v.u = gu.w; s1 = __builtin_amdgcn_fdot2(v.h, wv[i+3], s1, false);
    ALD(g0, 0) ALD(g1, 4) ALD(g2, 8) ALD(g3, 12)
#undef ALD
    Al_s[ALX(j)] = s0 + s1;
  }
  __syncthreads();

  // ---- phase 1: p = exp(e) for 2 rows x 32 j; local row sums ----
  {
    unsigned* erow0 = &e_s[r0][jg * 16];
    unsigned* erow1 = &e_s[r0 + 16][jg * 16];
    const int* adjp0 = adj + (size_t)(i0 + r0) * NN + jg * 32;
    const int* adjp1 = adj + (size_t)(i0 + r0 + 16) * NN + jg * 32;
    float srow0 = 0.f, srow1 = 0.f;
#pragma unroll 2
    for (int g4 = 0; g4 < 8; ++g4) {
      const int4 m0 = ((const int4*)adjp0)[g4];
      const int4 m1 = ((const int4*)adjp1)[g4];
      float p0[4], p1[4];
#pragma unroll
      for (int k = 0; k < 4; ++k) {
        const int j = jg * 32 + 4 * g4 + k;
        const int jx = GLX(j);
        const uint4 g0 = gl4[0 * NN + jx], g1 = gl4[1 * NN + jx];
        const uint4 g2 = gl4[2 * NN + jx], g3 = gl4[3 * NN + jx];
        const float al = Al_s[ALX(j)];
        const float e0 = score16(g0, g1, g2, g3, qh, uh, al + a_r0);
        const float e1 = score16(g0, g1, g2, g3, qh2, uh, al + a_r1);
        const int mk = (k == 0) ? m0.x : (k == 1) ? m0.y : (k == 2) ? m0.z : m0.w;
        const int nk = (k == 0) ? m1.x : (k == 1) ? m1.y : (k == 2) ? m1.z : m1.w;
        p0[k] = mk ? __expf(e0) : 0.f;
        p1[k] = nk ? __expf(e1) : 0.f;
      }
      srow0 += (p0[0] + p0[1]) + (p0[2] + p0[3]);
      srow1 += (p1[0] + p1[1]) + (p1[2] + p1[3]);
      uint2 w0, w1;
      w0.x = pkrtz_u(p0[0], p0[1]);
      w0.y = pkrtz_u(p0[2], p0[3]);
      w1.x = pkrtz_u(p1[0], p1[1]);
      w1.y = pkrtz_u(p1[2], p1[3]);
      *(uint2*)&erow0[2 * g4] = w0;
      *(uint2*)&erow1[2 * g4] = w1;
    }
    s_part[jg][r0] = srow0;
    s_part[jg][r0 + 16] = srow1;
  }
  __syncthreads();

  // ---- phase 2': stage grT (fp16 v_perm) + row-sum reduce ----
  {
    const int fq = t & 7;    // f-quad
    const int jp0 = t >> 3;  // 0..31 (j-pair)
    const unsigned* gbase =
        (const unsigned*)(grh + (size_t)b * NN * HF + hh * FD) + 2 * fq;
#pragma unroll
    for (int s2 = 0; s2 < 8; ++s2) {
      const int jp = jp0 + 32 * s2;
      const uint2 A = *(const uint2*)(gbase + (size_t)(2 * jp) * 128);
      const uint2 Bv = *(const uint2*)(gbase + (size_t)(2 * jp + 1) * 128);
      // low16 = even j (matches pkrtz packing of p in e_s)
      ubuf[(4 * fq + 0) * GTS + jp] = __builtin_amdgcn_perm(Bv.x, A.x, 0x05040100u);
      ubuf[(4 * fq + 1) * GTS + jp] = __builtin_amdgcn_perm(Bv.x, A.x, 0x07060302u);
      ubuf[(4 * fq + 2) * GTS + jp] = __builtin_amdgcn_perm(Bv.y, A.y, 0x05040100u);
      ubuf[(4 * fq + 3) * GTS + jp] = __builtin_amdgcn_perm(Bv.y, A.y, 0x07060302u);
    }
    if (t < IT) {
      float s = 0.f;
#pragma unroll
      for (int c = 0; c < 16; ++c) s += s_part[c][t];
      inv_l[t] = 1.f / s;
    }
  }
  __syncthreads();

  // ---- phase 3: MFMA GEMM  C[32x32] = P . grT^T, one 16x16 tile/wave ----
  {
    const int lane = t & 63;
    const int wv3 = t >> 6;          // 0..3
    const int Mt = wv3 & 1, Nt = wv3 >> 1;
    const int l16 = lane & 15, q = lane >> 4;
    const unsigned* arow = &e_s[Mt * 16 + l16][0];       // A[m][k] packed p
    const unsigned* brow = &ubuf[(Nt * 16 + l16) * GTS]; // B[k][n]=grT[n][k]
    v4f acc = {0.f, 0.f, 0.f, 0.f};
#pragma unroll
    for (int s = 0; s < 16; ++s) {
      U8 a; a.u4 = *(const uint4*)(arow + 16 * s + 4 * q);
      U8 bf; bf.u4 = *(const uint4*)(brow + 16 * s + 4 * q);
      acc = __builtin_amdgcn_mfma_f32_16x16x32_f16(a.h, bf.h, acc, 0, 0, 0);
    }
    // epilogue: D[row=q*4+r][col=l16], scale by inv_l, store
    float* op = out + (size_t)(b * NN + i0 + Mt * 16 + q * 4) * HF + hh * FD +
                Nt * 16 + l16;
#pragma unroll
    for (int r = 0; r < 4; ++r) {
      op[(size_t)r * HF] = acc[r] * inv_l[Mt * 16 + q * 4 + r];
    }
  }
}

// ---------------------------------------------------------------------------
extern "C" void kernel_launch(void* const* d_in, const int* in_sizes, int n_in,
                              void* d_out, int out_size, void* d_ws,
                              size_t ws_size, hipStream_t stream) {
  const float* h = (const float*)d_in[0];
  const int* adj = (const int*)d_in[1];
  const float* Wl = (const float*)d_in[2];
  const float* Wr = (const float*)d_in[3];
  const float* aw = (const float*)d_in[4];
  float* out = (float*)d_out;

  _Float16* glh = (_Float16*)d_ws;                                // 1 MB fp16
  _Float16* grh = (_Float16*)((char*)d_ws + (size_t)BB * NN * HF * 2);  // 1 MB

  dim3 gg(BB * NN / 8, 2, 1);
  gemm_dual<<<gg, 256, 0, stream>>>(h, Wl, Wr, glh, grh);

  dim3 ga(NH, NN / IT, BB);
  gat_attn<<<ga, 256, 0, stream>>>(glh, grh, adj, aw, out);
}